// Round 13
// baseline (205.961 us; speedup 1.0000x reference)
//
#include <hip/hip_runtime.h>
#include <hip/hip_bf16.h>
#include <stdint.h>

#define EMBED 1024
#define NH 16
#define HD 64
#define BATCH 2
#define QLEN 2048
#define CLEN 2048

typedef short short8 __attribute__((ext_vector_type(8)));
typedef unsigned short ushort8v __attribute__((ext_vector_type(8)));
typedef float f32x4 __attribute__((ext_vector_type(4)));
typedef float f32x16 __attribute__((ext_vector_type(16)));
typedef uint32_t u32x4 __attribute__((ext_vector_type(4)));

// softmax scale folded into Q projection: 1/sqrt(64) * log2(e)
#define QSCALE 0.18033688f

__device__ __forceinline__ void async_load16(const void* g, void* l) {
    __builtin_amdgcn_global_load_lds((const __attribute__((address_space(1))) void*)g,
                                     (__attribute__((address_space(3))) void*)l, 16, 0, 0);
}

__device__ __forceinline__ uint32_t pack2(float a, float b) {
    float2 f{a, b};
    __hip_bfloat162 t = __float22bfloat162_rn(f);
    uint32_t u;
    __builtin_memcpy(&u, &t, 4);
    return u;
}

// ---------------- prep: activations cvt (y=0,1) + weight transposes (y=2..5) ----------------
__global__ void prep(const float* __restrict__ query, const float* __restrict__ context,
                     __hip_bfloat16* __restrict__ qbf, __hip_bfloat16* __restrict__ cbf,
                     const float* __restrict__ W0, const float* __restrict__ W1,
                     const float* __restrict__ W2, const float* __restrict__ W3,
                     __hip_bfloat16* __restrict__ T0, __hip_bfloat16* __restrict__ T1,
                     __hip_bfloat16* __restrict__ T2, __hip_bfloat16* __restrict__ T3) {
    const int y = blockIdx.y;
    const int tid = threadIdx.x;
    if (y < 2) {
        const float* src = y ? context : query;
        __hip_bfloat16* dst = y ? cbf : qbf;
#pragma unroll
        for (int k = 0; k < 4; k++) {
            const int i = (blockIdx.x * 1024 + k * 256 + tid) * 4;
            float4 v = *(const float4*)(src + i);
            __hip_bfloat16 h[4];
            h[0] = __float2bfloat16(v.x);
            h[1] = __float2bfloat16(v.y);
            h[2] = __float2bfloat16(v.z);
            h[3] = __float2bfloat16(v.w);
            *(ushort4*)(dst + i) = *(const ushort4*)h;
        }
    } else {
        const int z = y - 2;
        const float* W = z == 0 ? W0 : z == 1 ? W1 : z == 2 ? W2 : W3;
        __hip_bfloat16* Wt = z == 0 ? T0 : z == 1 ? T1 : z == 2 ? T2 : T3;
        __shared__ float t[32][33];
        const int tx = tid & 31, ty = tid >> 5;
        const int n0 = (blockIdx.x & 31) * 32, k0 = (blockIdx.x >> 5) * 32;
#pragma unroll
        for (int r = 0; r < 4; r++)
            t[ty * 4 + r][tx] = W[(size_t)(k0 + ty * 4 + r) * EMBED + n0 + tx];
        __syncthreads();
#pragma unroll
        for (int r = 0; r < 4; r++)
            Wt[(size_t)(n0 + ty * 4 + r) * EMBED + k0 + tx] = __float2bfloat16(t[tx][ty * 4 + r]);
    }
}

// ---------------- 128x128 GEMM accumulate body (BK=32, B^T layout, K=1024) ----------------
// R18: single-barrier parity double-buffer (kept: neutral-positive, no cost).
__device__ __forceinline__ void gemm128_acc(
    const __hip_bfloat16* __restrict__ A, const __hip_bfloat16* __restrict__ Bt,
    int m0, int n0, __hip_bfloat16* As, __hip_bfloat16* Bs, f32x4 acc[4][4]) {
    const int K = EMBED;
    const int tid = threadIdx.x;
    const int wave = __builtin_amdgcn_readfirstlane(tid >> 6);
    const int lane = tid & 63, l15 = lane & 15, quad = lane >> 4;
    const int wm = (wave >> 1) * 64, wn = (wave & 1) * 64;
    const int srow = tid >> 2, sseg = (tid & 3) * 8;
    const int dst = wave * 512;
    const __hip_bfloat16* pa[2] = {A + (size_t)(m0 + srow) * K + sseg,
                                   A + (size_t)(m0 + 64 + srow) * K + sseg};
    const __hip_bfloat16* pb[2] = {Bt + (size_t)(n0 + srow) * K + sseg,
                                   Bt + (size_t)(n0 + 64 + srow) * K + sseg};
    // prologue: stage tile 0 into buf 0
#pragma unroll
    for (int s = 0; s < 2; s++) {
        async_load16(pa[s], As + s * 2048 + dst);
        async_load16(pb[s], Bs + s * 2048 + dst);
        pa[s] += 32; pb[s] += 32;
    }
    for (int k0 = 0; k0 < K; k0 += 32) {
        const int buf = (k0 >> 5) & 1;
        __syncthreads();  // tile k0 landed; buf^1 readers done
        if (k0 + 32 < K) {
            const int nb = buf ^ 1;
#pragma unroll
            for (int s = 0; s < 2; s++) {
                async_load16(pa[s], As + nb * 4096 + s * 2048 + dst);
                async_load16(pb[s], Bs + nb * 4096 + s * 2048 + dst);
                pa[s] += 32; pb[s] += 32;
            }
        }
        const __hip_bfloat16* Ab = As + buf * 4096;
        const __hip_bfloat16* Bb = Bs + buf * 4096;
        short8 af[4], bf[4];
#pragma unroll
        for (int t = 0; t < 4; t++) {
            af[t] = *(const short8*)(Ab + (wm + t * 16 + l15) * 32 + quad * 8);
            bf[t] = *(const short8*)(Bb + (wn + t * 16 + l15) * 32 + quad * 8);
        }
#pragma unroll
        for (int mt = 0; mt < 4; mt++)
#pragma unroll
            for (int nt = 0; nt < 4; nt++)
                acc[mt][nt] = __builtin_amdgcn_mfma_f32_16x16x32_bf16(af[mt], bf[nt], acc[mt][nt], 0, 0, 0);
    }
}

// ---------------- fused Q + K + V projections (V^T via LDS bounce, Q pre-scaled) ----------------
__global__ __launch_bounds__(256, 3) void proj128(
    const __hip_bfloat16* __restrict__ qbf, const __hip_bfloat16* __restrict__ cbf,
    const __hip_bfloat16* __restrict__ Wqt, const __hip_bfloat16* __restrict__ Wkvt,
    const float* __restrict__ bq, const float* __restrict__ bk, const float* __restrict__ bv,
    __hip_bfloat16* __restrict__ Qp, __hip_bfloat16* __restrict__ Kp, __hip_bfloat16* __restrict__ Vtr) {
    __shared__ __hip_bfloat16 smem[16384];  // As[2][4096] + Bs[2][4096]; T[64][136] reuses front
    __hip_bfloat16* As = smem;
    __hip_bfloat16* Bs = smem + 8192;
    const int j = blockIdx.x;
    const int blk = (j & 7) * 96 + (j >> 3);   // XCD swizzle
    const __hip_bfloat16 *A, *Bt;
    int m0, n0;
    if (blk < 256) {
        A = qbf; Bt = Wqt; m0 = (blk >> 3) * 128; n0 = (blk & 7) * 128;
    } else {
        const int f = blk - 256;
        A = cbf; Bt = Wkvt; m0 = (f >> 4) * 128; n0 = (f & 15) * 128;
    }
    f32x4 acc[4][4] = {};
    gemm128_acc(A, Bt, m0, n0, As, Bs, acc);

    const int tid = threadIdx.x;
    const int wave = __builtin_amdgcn_readfirstlane(tid >> 6);
    const int lane = tid & 63, l15 = lane & 15, quad = lane >> 4;
    const int wm = (wave >> 1) * 64, wn = (wave & 1) * 64;

    if (blk >= 256 && n0 >= 1024) {
        // V block: transpose 128x128 via LDS (two 64-col halves), coalesced writes
        const int cb = n0 - 1024;
        const int b2 = m0 >> 11;
        const int tokb = m0 & 2047;
        __hip_bfloat16* T = smem;  // 64 x 136
#pragma unroll
        for (int hh = 0; hh < 2; hh++) {
            __syncthreads();
            if ((wn >> 6) == hh) {
#pragma unroll
                for (int nt = 0; nt < 4; nt++) {
                    const int cn = nt * 16 + l15;
                    const float bvv = bv[cb + hh * 64 + cn];
#pragma unroll
                    for (int mt = 0; mt < 4; mt++) {
                        const int m = wm + mt * 16 + quad * 4;
                        __hip_bfloat16 vb[4];
#pragma unroll
                        for (int r = 0; r < 4; r++) vb[r] = __float2bfloat16(acc[mt][nt][r] + bvv);
                        *(ushort4*)(T + cn * 136 + m) = *(const ushort4*)vb;
                    }
                }
            }
            __syncthreads();
            const int r = tid >> 2;
            const int seg = (tid & 3) * 32;
            unsigned short* dst = (unsigned short*)Vtr +
                (size_t)(b2 * 1024 + cb + hh * 64 + r) * CLEN + tokb + seg;
            const unsigned short* srcp = (const unsigned short*)(T + r * 136 + seg);
#pragma unroll
            for (int u = 0; u < 4; u++)
                *(ushort8v*)(dst + u * 8) = *(const ushort8v*)(srcp + u * 8);
        }
    } else {
        const bool isQ = (blk < 256);
        const float* bias = isQ ? bq : bk;
        __hip_bfloat16* C = isQ ? Qp : Kp;
        const float sc = isQ ? QSCALE : 1.0f;
#pragma unroll
        for (int mt = 0; mt < 4; mt++) {
#pragma unroll
            for (int nt = 0; nt < 4; nt++) {
                const int c = n0 + wn + nt * 16 + l15;
                const float bvv = bias[c];
                const int r0 = m0 + wm + mt * 16 + quad * 4;
#pragma unroll
                for (int r = 0; r < 4; r++)
                    C[(size_t)(r0 + r) * 1024 + c] = __float2bfloat16((acc[mt][nt][r] + bvv) * sc);
            }
        }
    }
}

// ---------------- output projection: 64x128 tiles, fp32 out, XCD swizzle ----------------
// R20 config kept (R18 body + (256,2)); R18/R19/R20 A/B resolved to noise.
__global__ __launch_bounds__(256, 2) void oproj(
    const __hip_bfloat16* __restrict__ A, const __hip_bfloat16* __restrict__ Bt,
    const float* __restrict__ bias, float* __restrict__ C) {
    __shared__ __hip_bfloat16 As[2][64 * 32];
    __shared__ __hip_bfloat16 Bs[2][128 * 32];
    const int K = EMBED, N = EMBED;
    const int j = blockIdx.x;
    const int L = (j & 7) * 64 + (j >> 3);
    const int m0 = (L >> 3) * 64, n0 = (L & 7) * 128;
    const int tid = threadIdx.x;
    const int wave = __builtin_amdgcn_readfirstlane(tid >> 6);
    const int lane = tid & 63, l15 = lane & 15, quad = lane >> 4;
    const int wm = (wave & 1) * 32, wn = (wave >> 1) * 64;
    const int srow = tid >> 2, sseg = (tid & 3) * 8;
    const int dst = wave * 512;
    const __hip_bfloat16* pA = A + (size_t)(m0 + srow) * K + sseg;
    const __hip_bfloat16* pB[2] = {Bt + (size_t)(n0 + srow) * K + sseg,
                                   Bt + (size_t)(n0 + 64 + srow) * K + sseg};
    f32x4 acc[2][4] = {};
    // prologue: stage tile 0 into buf 0
    async_load16(pA, As[0] + dst);
    pA += 32;
#pragma unroll
    for (int s = 0; s < 2; s++) {
        async_load16(pB[s], Bs[0] + s * 2048 + dst);
        pB[s] += 32;
    }
    for (int k0 = 0; k0 < K; k0 += 32) {
        const int buf = (k0 >> 5) & 1;
        __syncthreads();  // tile k0 landed; buf^1 readers done
        if (k0 + 32 < K) {
            const int nb = buf ^ 1;
            async_load16(pA, As[nb] + dst);
            pA += 32;
#pragma unroll
            for (int s = 0; s < 2; s++) {
                async_load16(pB[s], Bs[nb] + s * 2048 + dst);
                pB[s] += 32;
            }
        }
        short8 af[2], bf[4];
#pragma unroll
        for (int t = 0; t < 2; t++)
            af[t] = *(const short8*)(As[buf] + (wm + t * 16 + l15) * 32 + quad * 8);
#pragma unroll
        for (int t = 0; t < 4; t++)
            bf[t] = *(const short8*)(Bs[buf] + (wn + t * 16 + l15) * 32 + quad * 8);
#pragma unroll
        for (int mt = 0; mt < 2; mt++)
#pragma unroll
            for (int nt = 0; nt < 4; nt++)
                acc[mt][nt] = __builtin_amdgcn_mfma_f32_16x16x32_bf16(af[mt], bf[nt], acc[mt][nt], 0, 0, 0);
    }
#pragma unroll
    for (int mt = 0; mt < 2; mt++) {
#pragma unroll
        for (int nt = 0; nt < 4; nt++) {
            const int c = n0 + wn + nt * 16 + l15;
            const float bvv = bias[c];
            const int r0 = m0 + wm + mt * 16 + quad * 4;
#pragma unroll
            for (int r = 0; r < 4; r++)
                C[(size_t)(r0 + r) * N + c] = acc[mt][nt][r] + bvv;
        }
    }
}

// ---------------- flash attention: 32x32x16 MFMA, S^T form ----------------
// R21: dependency-chain surgery inside the proven R19 period structure (no sync
// changes). Post-mortem model: wall 7590 cyc/period vs ~3000 of pipe demand; stall
// is correlated dependency chains at 2 barrier-synced waves/SIMD. Two fixes:
// (a) PV accumulator split 2->4 (oA=tp0, oB=tp1, merged in epilogue): PV becomes
//     4 chains of 2 per hh, and the kernel-length o-chain depth halves.
// (b) hh=1's kf fragments prefetched during hh=0's softmax/PV (~120cyc LDS latency
//     hidden under ~1000cyc of independent work; compiler didn't hoist — VGPR was
//     108 of 256 budget).
// Spill guard: WRITE_SIZE must stay 8192 KB; conflict guard: 0.
// Conflict-free LDS swizzle: phys granule = logical ^ (row&7) ^ (row>>3).
__global__ __launch_bounds__(256, 2) void flash_attn(
    const __hip_bfloat16* __restrict__ Q, const __hip_bfloat16* __restrict__ K,
    const __hip_bfloat16* __restrict__ Vt, __hip_bfloat16* __restrict__ O) {
    __shared__ __hip_bfloat16 Ks[2][2][64 * 64];
    __shared__ __hip_bfloat16 Vs[2][2][64 * 64];
    const int tid = threadIdx.x;
    const int wave = __builtin_amdgcn_readfirstlane(tid >> 6);
    const int lane = tid & 63, l31 = lane & 31, hbit = lane >> 5;
    const int j = blockIdx.x;
    const int L = (j & 7) * 64 + (j >> 3);  // XCD swizzle: 64 consecutive blocks/XCD
    const int hy = L >> 4;                  // b*16 + h
    const int b = hy >> 4, h = hy & 15;
    const int q0 = (L & 15) * 128;
    const size_t kbase = (size_t)b * CLEN * EMBED + (size_t)h * HD;
    const size_t vtbase = (size_t)((b * NH + h) * HD) * CLEN;
    const int srow8 = lane >> 3;               // 0..7
    const int sgb = (lane & 7) ^ srow8;        // swizzle base; per-issue: sgb ^ i
    const int i0 = wave * 2, i1 = wave * 2 + 1;

    const __hip_bfloat16* qptr =
        Q + (size_t)(b * QLEN + q0 + wave * 32 + l31) * EMBED + h * HD + hbit * 8;
    short8 qf[4];
#pragma unroll
    for (int t = 0; t < 4; t++) qf[t] = *(const short8*)(qptr + t * 16);

    f32x16 oA[2] = {}, oB[2] = {};
    float lsA = 0.f, lsB = 0.f, lsC = 0.f, lsD = 0.f;

    // running staging pointers (advance by one 128-c period per iteration)
    const __hip_bfloat16* pk0 = K + kbase + (size_t)(i0 * 8 + srow8) * EMBED + (sgb ^ i0) * 8;
    const __hip_bfloat16* pk1 = K + kbase + (size_t)(i1 * 8 + srow8) * EMBED + (sgb ^ i1) * 8;
    const __hip_bfloat16* pv0 = Vt + vtbase + (size_t)(i0 * 8 + srow8) * CLEN + (sgb ^ i0) * 8;
    const __hip_bfloat16* pv1 = Vt + vtbase + (size_t)(i1 * 8 + srow8) * CLEN + (sgb ^ i1) * 8;

    // prologue: stage period 0 (subs 0,1) into buf 0
#pragma unroll
    for (int s = 0; s < 2; s++) {
        async_load16(pk0 + (size_t)s * 64 * EMBED, Ks[0][s] + i0 * 512);
        async_load16(pk1 + (size_t)s * 64 * EMBED, Ks[0][s] + i1 * 512);
        async_load16(pv0 + s * 64, Vs[0][s] + i0 * 512);
        async_load16(pv1 + s * 64, Vs[0][s] + i1 * 512);
    }
    pk0 += (size_t)128 * EMBED; pk1 += (size_t)128 * EMBED;
    pv0 += 128; pv1 += 128;

    const int rsw0 = (l31 & 7) ^ (l31 >> 3);              // row = l31       (mc=0)
    const int rsw1 = (l31 & 7) ^ (4 + (l31 >> 3));        // row = 32 + l31  (mc=1)

    for (int t = 0; t < 16; ++t) {
        const int cur = t & 1;
        __syncthreads();  // period t landed (vmcnt drained); buf cur^1 readers done
        if (t < 15) {
#pragma unroll
            for (int s = 0; s < 2; s++) {
                async_load16(pk0 + (size_t)s * 64 * EMBED, Ks[cur ^ 1][s] + i0 * 512);
                async_load16(pk1 + (size_t)s * 64 * EMBED, Ks[cur ^ 1][s] + i1 * 512);
                async_load16(pv0 + s * 64, Vs[cur ^ 1][s] + i0 * 512);
                async_load16(pv1 + s * 64, Vs[cur ^ 1][s] + i1 * 512);
            }
            pk0 += (size_t)128 * EMBED; pk1 += (size_t)128 * EMBED;
            pv0 += 128; pv1 += 128;
        }

        // kf for hh=0 (hh=1's kf is prefetched inside the hh=0 body, under softmax/PV)
        short8 kfc[2][4], kfn[2][4];
        {
            const __hip_bfloat16* stK0 = Ks[cur][0];
#pragma unroll
            for (int kc = 0; kc < 4; kc++) {
                kfc[0][kc] = *(const short8*)(stK0 + l31 * 64 + ((2 * kc + hbit) ^ rsw0) * 8);
                kfc[1][kc] = *(const short8*)(stK0 + (32 + l31) * 64 + ((2 * kc + hbit) ^ rsw1) * 8);
            }
        }

#pragma unroll
        for (int hh = 0; hh < 2; hh++) {
            const __hip_bfloat16* stV = Vs[cur][hh];

            // ---- phase 1: QK^T both halves, both accumulators live ----
            f32x16 sv0 = {}, sv1 = {};
            __builtin_amdgcn_s_setprio(1);
#pragma unroll
            for (int kc = 0; kc < 4; kc++) {
                sv0 = __builtin_amdgcn_mfma_f32_32x32x16_bf16(kfc[0][kc], qf[kc], sv0, 0, 0, 0);
                sv1 = __builtin_amdgcn_mfma_f32_32x32x16_bf16(kfc[1][kc], qf[kc], sv1, 0, 0, 0);
            }
            __builtin_amdgcn_s_setprio(0);

            // ---- phase 2: prefetch V fragments + next half's K fragments ----
            short8 vf[2][4];
#pragma unroll
            for (int dm = 0; dm < 2; dm++) {
                const int vsw = dm ? rsw1 : rsw0;
                const __hip_bfloat16* vr = stV + (dm * 32 + l31) * 64;
#pragma unroll
                for (int k2 = 0; k2 < 4; k2++)
                    vf[dm][k2] = *(const short8*)(vr + ((2 * k2 + hbit) ^ vsw) * 8);
            }
            if (hh == 0) {
                const __hip_bfloat16* stK1 = Ks[cur][1];
#pragma unroll
                for (int kc = 0; kc < 4; kc++) {
                    kfn[0][kc] = *(const short8*)(stK1 + l31 * 64 + ((2 * kc + hbit) ^ rsw0) * 8);
                    kfn[1][kc] = *(const short8*)(stK1 + (32 + l31) * 64 + ((2 * kc + hbit) ^ rsw1) * 8);
                }
            }

            // ---- phase 3: softmax both halves (32 independent exp2) ----
            uint32_t dw[2][8];
#pragma unroll
            for (int i = 0; i < 8; i++) {
                const float a0 = __builtin_amdgcn_exp2f(sv0[2 * i]);
                const float a1 = __builtin_amdgcn_exp2f(sv0[2 * i + 1]);
                const float b0 = __builtin_amdgcn_exp2f(sv1[2 * i]);
                const float b1 = __builtin_amdgcn_exp2f(sv1[2 * i + 1]);
                if (i & 1) { lsB += a0 + a1; lsD += b0 + b1; }
                else       { lsA += a0 + a1; lsC += b0 + b1; }
                dw[0][i] = pack2(a0, a1);
                dw[1][i] = pack2(b0, b1);
            }

            // ---- phase 4: permlane + PV on prefetched vf (4 accumulator chains) ----
#pragma unroll
            for (int mc = 0; mc < 2; mc++) {
#pragma unroll
                for (int tp = 0; tp < 2; tp++) {
                    u32x4 fb;
#if __has_builtin(__builtin_amdgcn_permlane32_swap)
                    {
                        auto s02 = __builtin_amdgcn_permlane32_swap(dw[mc][4 * tp + 0], dw[mc][4 * tp + 2], false, false);
                        auto s13 = __builtin_amdgcn_permlane32_swap(dw[mc][4 * tp + 1], dw[mc][4 * tp + 3], false, false);
                        fb[0] = s02[0];
                        fb[1] = s13[0];
                        fb[2] = s02[1];
                        fb[3] = s13[1];
                    }
#else
                    {
                        const uint32_t a0 = hbit ? dw[mc][4 * tp + 2] : dw[mc][4 * tp + 0];
                        const uint32_t a1 = hbit ? dw[mc][4 * tp + 3] : dw[mc][4 * tp + 1];
                        const uint32_t b0 = hbit ? dw[mc][4 * tp + 0] : dw[mc][4 * tp + 2];
                        const uint32_t b1 = hbit ? dw[mc][4 * tp + 1] : dw[mc][4 * tp + 3];
                        const uint32_t x0 = (uint32_t)__shfl_xor((int)b0, 32);
                        const uint32_t x1 = (uint32_t)__shfl_xor((int)b1, 32);
                        fb[0] = hbit ? x0 : a0;
                        fb[1] = hbit ? x1 : a1;
                        fb[2] = hbit ? a0 : x0;
                        fb[3] = hbit ? a1 : x1;
                    }
#endif
                    const short8 pfr = __builtin_bit_cast(short8, fb);
                    const int kc2 = mc * 2 + tp;
                    __builtin_amdgcn_s_setprio(1);
                    if (tp == 0) {
                        oA[0] = __builtin_amdgcn_mfma_f32_32x32x16_bf16(vf[0][kc2], pfr, oA[0], 0, 0, 0);
                        oA[1] = __builtin_amdgcn_mfma_f32_32x32x16_bf16(vf[1][kc2], pfr, oA[1], 0, 0, 0);
                    } else {
                        oB[0] = __builtin_amdgcn_mfma_f32_32x32x16_bf16(vf[0][kc2], pfr, oB[0], 0, 0, 0);
                        oB[1] = __builtin_amdgcn_mfma_f32_32x32x16_bf16(vf[1][kc2], pfr, oB[1], 0, 0, 0);
                    }
                    __builtin_amdgcn_s_setprio(0);
                }
            }

            // next half consumes the prefetched K fragments
#pragma unroll
            for (int kc = 0; kc < 4; kc++) {
                kfc[0][kc] = kfn[0][kc];
                kfc[1][kc] = kfn[1][kc];
            }
        }
    }

    // ---- merge split accumulators, normalize & store ----
    f32x16 o[2];
    o[0] = oA[0] + oB[0];
    o[1] = oA[1] + oB[1];
    float lsum = (lsA + lsB) + (lsC + lsD);
    lsum += __shfl_xor(lsum, 32);
    const float inv = 1.0f / lsum;
    const int q = q0 + wave * 32 + l31;
    __hip_bfloat16* orow = O + (size_t)(b * QLEN + q) * EMBED + h * HD;
#pragma unroll
    for (int dm = 0; dm < 2; dm++) {
#pragma unroll
        for (int g = 0; g < 4; g++) {
            __hip_bfloat16 ob[4];
#pragma unroll
            for (int r = 0; r < 4; r++) ob[r] = __float2bfloat16(o[dm][g * 4 + r] * inv);
            *(ushort4*)(orow + dm * 32 + hbit * 4 + g * 8) = *(const ushort4*)ob;
        }
    }
}

extern "C" void kernel_launch(void* const* d_in, const int* in_sizes, int n_in,
                              void* d_out, int out_size, void* d_ws, size_t ws_size,
                              hipStream_t stream) {
    const float* query = (const float*)d_in[0];
    const float* context = (const float*)d_in[1];
    const float* Wq = (const float*)d_in[2];
    const float* bq = (const float*)d_in[3];
    const float* Wk = (const float*)d_in[4];
    const float* bk = (const float*)d_in[5];
    const float* Wv = (const float*)d_in[6];
    const float* bv = (const float*)d_in[7];
    const float* Wo = (const float*)d_in[8];
    const float* bo = (const float*)d_in[9];
    float* out = (float*)d_out;

    const int NTOK = BATCH * QLEN;   // 4096
    const int NACT = NTOK * EMBED;   // 4,194,304
    const int NW = EMBED * EMBED;    // 1,048,576

    __hip_bfloat16* qbf = (__hip_bfloat16*)d_ws;
    __hip_bfloat16* cbf = qbf + NACT;
    __hip_bfloat16* Wqt = cbf + NACT;
    __hip_bfloat16* Wkt = Wqt + NW;
    __hip_bfloat16* Wvt = Wkt + NW;
    __hip_bfloat16* Wot = Wvt + NW;
    __hip_bfloat16* Qp = Wot + NW;
    __hip_bfloat16* Kp = Qp + NACT;
    __hip_bfloat16* Vtr = Kp + NACT;
    __hip_bfloat16* att = Vtr + NACT;

    prep<<<dim3(1024, 6), 256, 0, stream>>>(query, context, qbf, cbf,
                                            Wq, Wk, Wv, Wo, Wqt, Wkt, Wvt, Wot);

    proj128<<<768, 256, 0, stream>>>(qbf, cbf, Wqt, Wkt, bq, bk, bv, Qp, Kp, Vtr);

    flash_attn<<<512, 256, 0, stream>>>(Qp, Kp, Vtr, att);

    oproj<<<512, 256, 0, stream>>>(att, Wot, bo, out);
}

// Round 14
// 201.076 us; speedup vs baseline: 1.0243x; 1.0243x over previous
//
#include <hip/hip_runtime.h>
#include <hip/hip_bf16.h>
#include <stdint.h>

#define EMBED 1024
#define NH 16
#define HD 64
#define BATCH 2
#define QLEN 2048
#define CLEN 2048

typedef short short8 __attribute__((ext_vector_type(8)));
typedef unsigned short ushort8v __attribute__((ext_vector_type(8)));
typedef float f32x4 __attribute__((ext_vector_type(4)));
typedef float f32x16 __attribute__((ext_vector_type(16)));
typedef uint32_t u32x4 __attribute__((ext_vector_type(4)));

// softmax scale folded into Q projection: 1/sqrt(64) * log2(e)
#define QSCALE 0.18033688f

__device__ __forceinline__ void async_load16(const void* g, void* l) {
    __builtin_amdgcn_global_load_lds((const __attribute__((address_space(1))) void*)g,
                                     (__attribute__((address_space(3))) void*)l, 16, 0, 0);
}

__device__ __forceinline__ uint32_t pack2(float a, float b) {
    float2 f{a, b};
    __hip_bfloat162 t = __float22bfloat162_rn(f);
    uint32_t u;
    __builtin_memcpy(&u, &t, 4);
    return u;
}

// ---------------- prep: activations cvt (y=0,1) + weight transposes (y=2..5) ----------------
__global__ void prep(const float* __restrict__ query, const float* __restrict__ context,
                     __hip_bfloat16* __restrict__ qbf, __hip_bfloat16* __restrict__ cbf,
                     const float* __restrict__ W0, const float* __restrict__ W1,
                     const float* __restrict__ W2, const float* __restrict__ W3,
                     __hip_bfloat16* __restrict__ T0, __hip_bfloat16* __restrict__ T1,
                     __hip_bfloat16* __restrict__ T2, __hip_bfloat16* __restrict__ T3) {
    const int y = blockIdx.y;
    const int tid = threadIdx.x;
    if (y < 2) {
        const float* src = y ? context : query;
        __hip_bfloat16* dst = y ? cbf : qbf;
#pragma unroll
        for (int k = 0; k < 4; k++) {
            const int i = (blockIdx.x * 1024 + k * 256 + tid) * 4;
            float4 v = *(const float4*)(src + i);
            __hip_bfloat16 h[4];
            h[0] = __float2bfloat16(v.x);
            h[1] = __float2bfloat16(v.y);
            h[2] = __float2bfloat16(v.z);
            h[3] = __float2bfloat16(v.w);
            *(ushort4*)(dst + i) = *(const ushort4*)h;
        }
    } else {
        const int z = y - 2;
        const float* W = z == 0 ? W0 : z == 1 ? W1 : z == 2 ? W2 : W3;
        __hip_bfloat16* Wt = z == 0 ? T0 : z == 1 ? T1 : z == 2 ? T2 : T3;
        __shared__ float t[32][33];
        const int tx = tid & 31, ty = tid >> 5;
        const int n0 = (blockIdx.x & 31) * 32, k0 = (blockIdx.x >> 5) * 32;
#pragma unroll
        for (int r = 0; r < 4; r++)
            t[ty * 4 + r][tx] = W[(size_t)(k0 + ty * 4 + r) * EMBED + n0 + tx];
        __syncthreads();
#pragma unroll
        for (int r = 0; r < 4; r++)
            Wt[(size_t)(n0 + ty * 4 + r) * EMBED + k0 + tx] = __float2bfloat16(t[tx][ty * 4 + r]);
    }
}

// ---------------- 128x128 GEMM accumulate body (BK=32, B^T layout, K=1024) ----------------
// R18: single-barrier parity double-buffer (kept: neutral-positive, no cost).
__device__ __forceinline__ void gemm128_acc(
    const __hip_bfloat16* __restrict__ A, const __hip_bfloat16* __restrict__ Bt,
    int m0, int n0, __hip_bfloat16* As, __hip_bfloat16* Bs, f32x4 acc[4][4]) {
    const int K = EMBED;
    const int tid = threadIdx.x;
    const int wave = __builtin_amdgcn_readfirstlane(tid >> 6);
    const int lane = tid & 63, l15 = lane & 15, quad = lane >> 4;
    const int wm = (wave >> 1) * 64, wn = (wave & 1) * 64;
    const int srow = tid >> 2, sseg = (tid & 3) * 8;
    const int dst = wave * 512;
    const __hip_bfloat16* pa[2] = {A + (size_t)(m0 + srow) * K + sseg,
                                   A + (size_t)(m0 + 64 + srow) * K + sseg};
    const __hip_bfloat16* pb[2] = {Bt + (size_t)(n0 + srow) * K + sseg,
                                   Bt + (size_t)(n0 + 64 + srow) * K + sseg};
    // prologue: stage tile 0 into buf 0
#pragma unroll
    for (int s = 0; s < 2; s++) {
        async_load16(pa[s], As + s * 2048 + dst);
        async_load16(pb[s], Bs + s * 2048 + dst);
        pa[s] += 32; pb[s] += 32;
    }
    for (int k0 = 0; k0 < K; k0 += 32) {
        const int buf = (k0 >> 5) & 1;
        __syncthreads();  // tile k0 landed; buf^1 readers done
        if (k0 + 32 < K) {
            const int nb = buf ^ 1;
#pragma unroll
            for (int s = 0; s < 2; s++) {
                async_load16(pa[s], As + nb * 4096 + s * 2048 + dst);
                async_load16(pb[s], Bs + nb * 4096 + s * 2048 + dst);
                pa[s] += 32; pb[s] += 32;
            }
        }
        const __hip_bfloat16* Ab = As + buf * 4096;
        const __hip_bfloat16* Bb = Bs + buf * 4096;
        short8 af[4], bf[4];
#pragma unroll
        for (int t = 0; t < 4; t++) {
            af[t] = *(const short8*)(Ab + (wm + t * 16 + l15) * 32 + quad * 8);
            bf[t] = *(const short8*)(Bb + (wn + t * 16 + l15) * 32 + quad * 8);
        }
#pragma unroll
        for (int mt = 0; mt < 4; mt++)
#pragma unroll
            for (int nt = 0; nt < 4; nt++)
                acc[mt][nt] = __builtin_amdgcn_mfma_f32_16x16x32_bf16(af[mt], bf[nt], acc[mt][nt], 0, 0, 0);
    }
}

// ---------------- fused Q + K + V projections (V^T via LDS bounce, Q pre-scaled) ----------------
__global__ __launch_bounds__(256, 3) void proj128(
    const __hip_bfloat16* __restrict__ qbf, const __hip_bfloat16* __restrict__ cbf,
    const __hip_bfloat16* __restrict__ Wqt, const __hip_bfloat16* __restrict__ Wkvt,
    const float* __restrict__ bq, const float* __restrict__ bk, const float* __restrict__ bv,
    __hip_bfloat16* __restrict__ Qp, __hip_bfloat16* __restrict__ Kp, __hip_bfloat16* __restrict__ Vtr) {
    __shared__ __hip_bfloat16 smem[16384];  // As[2][4096] + Bs[2][4096]; T[64][136] reuses front
    __hip_bfloat16* As = smem;
    __hip_bfloat16* Bs = smem + 8192;
    const int j = blockIdx.x;
    const int blk = (j & 7) * 96 + (j >> 3);   // XCD swizzle
    const __hip_bfloat16 *A, *Bt;
    int m0, n0;
    if (blk < 256) {
        A = qbf; Bt = Wqt; m0 = (blk >> 3) * 128; n0 = (blk & 7) * 128;
    } else {
        const int f = blk - 256;
        A = cbf; Bt = Wkvt; m0 = (f >> 4) * 128; n0 = (f & 15) * 128;
    }
    f32x4 acc[4][4] = {};
    gemm128_acc(A, Bt, m0, n0, As, Bs, acc);

    const int tid = threadIdx.x;
    const int wave = __builtin_amdgcn_readfirstlane(tid >> 6);
    const int lane = tid & 63, l15 = lane & 15, quad = lane >> 4;
    const int wm = (wave >> 1) * 64, wn = (wave & 1) * 64;

    if (blk >= 256 && n0 >= 1024) {
        // V block: transpose 128x128 via LDS (two 64-col halves), coalesced writes
        const int cb = n0 - 1024;
        const int b2 = m0 >> 11;
        const int tokb = m0 & 2047;
        __hip_bfloat16* T = smem;  // 64 x 136
#pragma unroll
        for (int hh = 0; hh < 2; hh++) {
            __syncthreads();
            if ((wn >> 6) == hh) {
#pragma unroll
                for (int nt = 0; nt < 4; nt++) {
                    const int cn = nt * 16 + l15;
                    const float bvv = bv[cb + hh * 64 + cn];
#pragma unroll
                    for (int mt = 0; mt < 4; mt++) {
                        const int m = wm + mt * 16 + quad * 4;
                        __hip_bfloat16 vb[4];
#pragma unroll
                        for (int r = 0; r < 4; r++) vb[r] = __float2bfloat16(acc[mt][nt][r] + bvv);
                        *(ushort4*)(T + cn * 136 + m) = *(const ushort4*)vb;
                    }
                }
            }
            __syncthreads();
            const int r = tid >> 2;
            const int seg = (tid & 3) * 32;
            unsigned short* dst = (unsigned short*)Vtr +
                (size_t)(b2 * 1024 + cb + hh * 64 + r) * CLEN + tokb + seg;
            const unsigned short* srcp = (const unsigned short*)(T + r * 136 + seg);
#pragma unroll
            for (int u = 0; u < 4; u++)
                *(ushort8v*)(dst + u * 8) = *(const ushort8v*)(srcp + u * 8);
        }
    } else {
        const bool isQ = (blk < 256);
        const float* bias = isQ ? bq : bk;
        __hip_bfloat16* C = isQ ? Qp : Kp;
        const float sc = isQ ? QSCALE : 1.0f;
#pragma unroll
        for (int mt = 0; mt < 4; mt++) {
#pragma unroll
            for (int nt = 0; nt < 4; nt++) {
                const int c = n0 + wn + nt * 16 + l15;
                const float bvv = bias[c];
                const int r0 = m0 + wm + mt * 16 + quad * 4;
#pragma unroll
                for (int r = 0; r < 4; r++)
                    C[(size_t)(r0 + r) * 1024 + c] = __float2bfloat16((acc[mt][nt][r] + bvv) * sc);
            }
        }
    }
}

// ---------------- output projection: 64x128 tiles, fp32 out, XCD swizzle ----------------
// R20 config kept (R18 body + (256,2)); R18/R19/R20 A/B resolved to noise.
__global__ __launch_bounds__(256, 2) void oproj(
    const __hip_bfloat16* __restrict__ A, const __hip_bfloat16* __restrict__ Bt,
    const float* __restrict__ bias, float* __restrict__ C) {
    __shared__ __hip_bfloat16 As[2][64 * 32];
    __shared__ __hip_bfloat16 Bs[2][128 * 32];
    const int K = EMBED, N = EMBED;
    const int j = blockIdx.x;
    const int L = (j & 7) * 64 + (j >> 3);
    const int m0 = (L >> 3) * 64, n0 = (L & 7) * 128;
    const int tid = threadIdx.x;
    const int wave = __builtin_amdgcn_readfirstlane(tid >> 6);
    const int lane = tid & 63, l15 = lane & 15, quad = lane >> 4;
    const int wm = (wave & 1) * 32, wn = (wave >> 1) * 64;
    const int srow = tid >> 2, sseg = (tid & 3) * 8;
    const int dst = wave * 512;
    const __hip_bfloat16* pA = A + (size_t)(m0 + srow) * K + sseg;
    const __hip_bfloat16* pB[2] = {Bt + (size_t)(n0 + srow) * K + sseg,
                                   Bt + (size_t)(n0 + 64 + srow) * K + sseg};
    f32x4 acc[2][4] = {};
    // prologue: stage tile 0 into buf 0
    async_load16(pA, As[0] + dst);
    pA += 32;
#pragma unroll
    for (int s = 0; s < 2; s++) {
        async_load16(pB[s], Bs[0] + s * 2048 + dst);
        pB[s] += 32;
    }
    for (int k0 = 0; k0 < K; k0 += 32) {
        const int buf = (k0 >> 5) & 1;
        __syncthreads();  // tile k0 landed; buf^1 readers done
        if (k0 + 32 < K) {
            const int nb = buf ^ 1;
            async_load16(pA, As[nb] + dst);
            pA += 32;
#pragma unroll
            for (int s = 0; s < 2; s++) {
                async_load16(pB[s], Bs[nb] + s * 2048 + dst);
                pB[s] += 32;
            }
        }
        short8 af[2], bf[4];
#pragma unroll
        for (int t = 0; t < 2; t++)
            af[t] = *(const short8*)(As[buf] + (wm + t * 16 + l15) * 32 + quad * 8);
#pragma unroll
        for (int t = 0; t < 4; t++)
            bf[t] = *(const short8*)(Bs[buf] + (wn + t * 16 + l15) * 32 + quad * 8);
#pragma unroll
        for (int mt = 0; mt < 2; mt++)
#pragma unroll
            for (int nt = 0; nt < 4; nt++)
                acc[mt][nt] = __builtin_amdgcn_mfma_f32_16x16x32_bf16(af[mt], bf[nt], acc[mt][nt], 0, 0, 0);
    }
#pragma unroll
    for (int mt = 0; mt < 2; mt++) {
#pragma unroll
        for (int nt = 0; nt < 4; nt++) {
            const int c = n0 + wn + nt * 16 + l15;
            const float bvv = bias[c];
            const int r0 = m0 + wm + mt * 16 + quad * 4;
#pragma unroll
            for (int r = 0; r < 4; r++)
                C[(size_t)(r0 + r) * N + c] = acc[mt][nt][r] + bvv;
        }
    }
}

// ---------------- flash attention: 32x32x16 MFMA, S^T form ----------------
// FINAL (R19 structure): 128-c periods of two verbatim R15-layout 64x64 sub-tiles,
// 16 barriers, parity-dbuf, dual-sv QK + vf-prefetch + wide softmax + permlane.
// 50.3-50.6 µs, conflicts 0, VGPR 108, zero spill. R21's chain-split + kf-prefetch
// measured NULL and was reverted (simpler code wins at equal speed). Residual gap
// to HK-class (MfmaUtil 27% vs ~60%) is the 2-waves/SIMD barrier-synced regime;
// breaking it requires the full 8-phase counted-vmcnt schedule (not attemptable
// headlessly without race-screening).
// Conflict-free LDS swizzle: phys granule = logical ^ (row&7) ^ (row>>3).
__global__ __launch_bounds__(256, 2) void flash_attn(
    const __hip_bfloat16* __restrict__ Q, const __hip_bfloat16* __restrict__ K,
    const __hip_bfloat16* __restrict__ Vt, __hip_bfloat16* __restrict__ O) {
    __shared__ __hip_bfloat16 Ks[2][2][64 * 64];
    __shared__ __hip_bfloat16 Vs[2][2][64 * 64];
    const int tid = threadIdx.x;
    const int wave = __builtin_amdgcn_readfirstlane(tid >> 6);
    const int lane = tid & 63, l31 = lane & 31, hbit = lane >> 5;
    const int j = blockIdx.x;
    const int L = (j & 7) * 64 + (j >> 3);  // XCD swizzle: 64 consecutive blocks/XCD
    const int hy = L >> 4;                  // b*16 + h
    const int b = hy >> 4, h = hy & 15;
    const int q0 = (L & 15) * 128;
    const size_t kbase = (size_t)b * CLEN * EMBED + (size_t)h * HD;
    const size_t vtbase = (size_t)((b * NH + h) * HD) * CLEN;
    const int srow8 = lane >> 3;               // 0..7
    const int sgb = (lane & 7) ^ srow8;        // swizzle base; per-issue: sgb ^ i
    const int i0 = wave * 2, i1 = wave * 2 + 1;

    const __hip_bfloat16* qptr =
        Q + (size_t)(b * QLEN + q0 + wave * 32 + l31) * EMBED + h * HD + hbit * 8;
    short8 qf[4];
#pragma unroll
    for (int t = 0; t < 4; t++) qf[t] = *(const short8*)(qptr + t * 16);

    f32x16 o[2] = {};
    float lsA = 0.f, lsB = 0.f, lsC = 0.f, lsD = 0.f;

    // running staging pointers (advance by one 128-c period per iteration)
    const __hip_bfloat16* pk0 = K + kbase + (size_t)(i0 * 8 + srow8) * EMBED + (sgb ^ i0) * 8;
    const __hip_bfloat16* pk1 = K + kbase + (size_t)(i1 * 8 + srow8) * EMBED + (sgb ^ i1) * 8;
    const __hip_bfloat16* pv0 = Vt + vtbase + (size_t)(i0 * 8 + srow8) * CLEN + (sgb ^ i0) * 8;
    const __hip_bfloat16* pv1 = Vt + vtbase + (size_t)(i1 * 8 + srow8) * CLEN + (sgb ^ i1) * 8;

    // prologue: stage period 0 (subs 0,1) into buf 0
#pragma unroll
    for (int s = 0; s < 2; s++) {
        async_load16(pk0 + (size_t)s * 64 * EMBED, Ks[0][s] + i0 * 512);
        async_load16(pk1 + (size_t)s * 64 * EMBED, Ks[0][s] + i1 * 512);
        async_load16(pv0 + s * 64, Vs[0][s] + i0 * 512);
        async_load16(pv1 + s * 64, Vs[0][s] + i1 * 512);
    }
    pk0 += (size_t)128 * EMBED; pk1 += (size_t)128 * EMBED;
    pv0 += 128; pv1 += 128;

    const int rsw0 = (l31 & 7) ^ (l31 >> 3);              // row = l31       (mc=0)
    const int rsw1 = (l31 & 7) ^ (4 + (l31 >> 3));        // row = 32 + l31  (mc=1)

    for (int t = 0; t < 16; ++t) {
        const int cur = t & 1;
        __syncthreads();  // period t landed (vmcnt drained); buf cur^1 readers done
        if (t < 15) {
#pragma unroll
            for (int s = 0; s < 2; s++) {
                async_load16(pk0 + (size_t)s * 64 * EMBED, Ks[cur ^ 1][s] + i0 * 512);
                async_load16(pk1 + (size_t)s * 64 * EMBED, Ks[cur ^ 1][s] + i1 * 512);
                async_load16(pv0 + s * 64, Vs[cur ^ 1][s] + i0 * 512);
                async_load16(pv1 + s * 64, Vs[cur ^ 1][s] + i1 * 512);
            }
            pk0 += (size_t)128 * EMBED; pk1 += (size_t)128 * EMBED;
            pv0 += 128; pv1 += 128;
        }

#pragma unroll
        for (int hh = 0; hh < 2; hh++) {
            const __hip_bfloat16* stK = Ks[cur][hh];
            const __hip_bfloat16* stV = Vs[cur][hh];

            // ---- phase 1: QK^T both halves, both accumulators live ----
            short8 kf[2][4];
#pragma unroll
            for (int kc = 0; kc < 4; kc++) {
                kf[0][kc] = *(const short8*)(stK + l31 * 64 + ((2 * kc + hbit) ^ rsw0) * 8);
                kf[1][kc] = *(const short8*)(stK + (32 + l31) * 64 + ((2 * kc + hbit) ^ rsw1) * 8);
            }
            f32x16 sv0 = {}, sv1 = {};
            __builtin_amdgcn_s_setprio(1);
#pragma unroll
            for (int kc = 0; kc < 4; kc++) {
                sv0 = __builtin_amdgcn_mfma_f32_32x32x16_bf16(kf[0][kc], qf[kc], sv0, 0, 0, 0);
                sv1 = __builtin_amdgcn_mfma_f32_32x32x16_bf16(kf[1][kc], qf[kc], sv1, 0, 0, 0);
            }
            __builtin_amdgcn_s_setprio(0);

            // ---- phase 2: prefetch all V fragments (latency hides under softmax) ----
            short8 vf[2][4];
#pragma unroll
            for (int dm = 0; dm < 2; dm++) {
                const int vsw = dm ? rsw1 : rsw0;
                const __hip_bfloat16* vr = stV + (dm * 32 + l31) * 64;
#pragma unroll
                for (int k2 = 0; k2 < 4; k2++)
                    vf[dm][k2] = *(const short8*)(vr + ((2 * k2 + hbit) ^ vsw) * 8);
            }

            // ---- phase 3: softmax both halves (32 independent exp2) ----
            uint32_t dw[2][8];
#pragma unroll
            for (int i = 0; i < 8; i++) {
                const float a0 = __builtin_amdgcn_exp2f(sv0[2 * i]);
                const float a1 = __builtin_amdgcn_exp2f(sv0[2 * i + 1]);
                const float b0 = __builtin_amdgcn_exp2f(sv1[2 * i]);
                const float b1 = __builtin_amdgcn_exp2f(sv1[2 * i + 1]);
                if (i & 1) { lsB += a0 + a1; lsD += b0 + b1; }
                else       { lsA += a0 + a1; lsC += b0 + b1; }
                dw[0][i] = pack2(a0, a1);
                dw[1][i] = pack2(b0, b1);
            }

            // ---- phase 4: permlane + PV on prefetched vf ----
#pragma unroll
            for (int mc = 0; mc < 2; mc++) {
#pragma unroll
                for (int tp = 0; tp < 2; tp++) {
                    u32x4 fb;
#if __has_builtin(__builtin_amdgcn_permlane32_swap)
                    {
                        auto s02 = __builtin_amdgcn_permlane32_swap(dw[mc][4 * tp + 0], dw[mc][4 * tp + 2], false, false);
                        auto s13 = __builtin_amdgcn_permlane32_swap(dw[mc][4 * tp + 1], dw[mc][4 * tp + 3], false, false);
                        fb[0] = s02[0];
                        fb[1] = s13[0];
                        fb[2] = s02[1];
                        fb[3] = s13[1];
                    }
#else
                    {
                        const uint32_t a0 = hbit ? dw[mc][4 * tp + 2] : dw[mc][4 * tp + 0];
                        const uint32_t a1 = hbit ? dw[mc][4 * tp + 3] : dw[mc][4 * tp + 1];
                        const uint32_t b0 = hbit ? dw[mc][4 * tp + 0] : dw[mc][4 * tp + 2];
                        const uint32_t b1 = hbit ? dw[mc][4 * tp + 1] : dw[mc][4 * tp + 3];
                        const uint32_t x0 = (uint32_t)__shfl_xor((int)b0, 32);
                        const uint32_t x1 = (uint32_t)__shfl_xor((int)b1, 32);
                        fb[0] = hbit ? x0 : a0;
                        fb[1] = hbit ? x1 : a1;
                        fb[2] = hbit ? a0 : x0;
                        fb[3] = hbit ? a1 : x1;
                    }
#endif
                    const short8 pfr = __builtin_bit_cast(short8, fb);
                    const int kc2 = mc * 2 + tp;
                    __builtin_amdgcn_s_setprio(1);
                    o[0] = __builtin_amdgcn_mfma_f32_32x32x16_bf16(vf[0][kc2], pfr, o[0], 0, 0, 0);
                    o[1] = __builtin_amdgcn_mfma_f32_32x32x16_bf16(vf[1][kc2], pfr, o[1], 0, 0, 0);
                    __builtin_amdgcn_s_setprio(0);
                }
            }
        }
    }

    // ---- normalize & store (each wave owns its 32 q-rows completely) ----
    float lsum = (lsA + lsB) + (lsC + lsD);
    lsum += __shfl_xor(lsum, 32);
    const float inv = 1.0f / lsum;
    const int q = q0 + wave * 32 + l31;
    __hip_bfloat16* orow = O + (size_t)(b * QLEN + q) * EMBED + h * HD;
#pragma unroll
    for (int dm = 0; dm < 2; dm++) {
#pragma unroll
        for (int g = 0; g < 4; g++) {
            __hip_bfloat16 ob[4];
#pragma unroll
            for (int r = 0; r < 4; r++) ob[r] = __float2bfloat16(o[dm][g * 4 + r] * inv);
            *(ushort4*)(orow + dm * 32 + hbit * 4 + g * 8) = *(const ushort4*)ob;
        }
    }
}

extern "C" void kernel_launch(void* const* d_in, const int* in_sizes, int n_in,
                              void* d_out, int out_size, void* d_ws, size_t ws_size,
                              hipStream_t stream) {
    const float* query = (const float*)d_in[0];
    const float* context = (const float*)d_in[1];
    const float* Wq = (const float*)d_in[2];
    const float* bq = (const float*)d_in[3];
    const float* Wk = (const float*)d_in[4];
    const float* bk = (const float*)d_in[5];
    const float* Wv = (const float*)d_in[6];
    const float* bv = (const float*)d_in[7];
    const float* Wo = (const float*)d_in[8];
    const float* bo = (const float*)d_in[9];
    float* out = (float*)d_out;

    const int NTOK = BATCH * QLEN;   // 4096
    const int NACT = NTOK * EMBED;   // 4,194,304
    const int NW = EMBED * EMBED;    // 1,048,576

    __hip_bfloat16* qbf = (__hip_bfloat16*)d_ws;
    __hip_bfloat16* cbf = qbf + NACT;
    __hip_bfloat16* Wqt = cbf + NACT;
    __hip_bfloat16* Wkt = Wqt + NW;
    __hip_bfloat16* Wvt = Wkt + NW;
    __hip_bfloat16* Wot = Wvt + NW;
    __hip_bfloat16* Qp = Wot + NW;
    __hip_bfloat16* Kp = Qp + NACT;
    __hip_bfloat16* Vtr = Kp + NACT;
    __hip_bfloat16* att = Vtr + NACT;

    prep<<<dim3(1024, 6), 256, 0, stream>>>(query, context, qbf, cbf,
                                            Wq, Wk, Wv, Wo, Wqt, Wkt, Wvt, Wot);

    proj128<<<768, 256, 0, stream>>>(qbf, cbf, Wqt, Wkt, bq, bk, bv, Qp, Kp, Vtr);

    flash_attn<<<512, 256, 0, stream>>>(Qp, Kp, Vtr, att);

    oproj<<<512, 256, 0, stream>>>(att, Wot, bo, out);
}